// Round 19
// baseline (210.075 us; speedup 1.0000x reference)
//
#include <hip/hip_runtime.h>
#include <math.h>
#include <stdint.h>

#define N_NODES 50000
#define N_EDGES 800000
#define IN_DIM  512
#define OUT_DIM 256
#define NBLK_SCAN 49   // ceil(50000/1024)
#define NGEMM 1563     // ceil(50000/32)

typedef __attribute__((ext_vector_type(8))) short short8;
typedef __attribute__((ext_vector_type(4))) float f32x4;

__device__ inline unsigned f2bf(float x) {
  unsigned u = __float_as_uint(x);
  return (u + 0x7FFFu + ((u >> 16) & 1u)) >> 16;   // RNE
}
__device__ inline float bf2f(unsigned short h) {
  return __uint_as_float(((unsigned)h) << 16);
}

// async 16B global->LDS copy (lds dest = wave-uniform base; HW adds lane*16)
__device__ inline void gload_lds16(const void* g, void* l) {
  __builtin_amdgcn_global_load_lds(
      (const __attribute__((address_space(1))) unsigned int*)g,
      (__attribute__((address_space(3))) unsigned int*)l, 16, 0, 0);
}

// ---------------- K1: wconv [0,512) + deg_count [512,3637) + proj [3637,..) -
#define WCONV_BLKS 512
#define DEG_BLKS   3125
__global__ __launch_bounds__(256) void wconv_deg_proj(const float* __restrict__ W,
                      unsigned short* __restrict__ Wtp,
                      const int* __restrict__ dst, int* __restrict__ deg,
                      const float* __restrict__ feat,
                      const float* __restrict__ Wl, const float* __restrict__ bl,
                      const float* __restrict__ Wr, const float* __restrict__ br,
                      float* __restrict__ el, float* __restrict__ er) {
  if (blockIdx.x < WCONV_BLKS) {
    int i = blockIdx.x * 256 + threadIdx.x;   // over 131072
    int c = i & 255, k = i >> 8;
    int nt = c >> 4, kk = k >> 5;
    int lane = (((k & 31) >> 3) << 4) | (c & 15);
    int j = k & 7;
    Wtp[(((size_t)(nt * 16 + kk)) * 64 + lane) * 8 + j] =
        (unsigned short)f2bf(W[(size_t)k * OUT_DIM + c]);
  } else if (blockIdx.x < WCONV_BLKS + DEG_BLKS) {
    int e = (blockIdx.x - WCONV_BLKS) * 256 + threadIdx.x;
    if (e < N_EDGES) atomicAdd(&deg[dst[e]], 1);
  } else {
    // proj: one wave per node (round-1 proven body)
    int node = (blockIdx.x - WCONV_BLKS - DEG_BLKS) * 4 + (threadIdx.x >> 6);
    int lane = threadIdx.x & 63;
    if (node >= N_NODES) return;
    const float4* frow = (const float4*)(feat + (size_t)node * IN_DIM);
    const float4* wl4  = (const float4*)Wl;
    const float4* wr4  = (const float4*)Wr;
    float al = 0.f, ar = 0.f;
    #pragma unroll
    for (int j = lane; j < IN_DIM / 4; j += 64) {
      float4 f = frow[j];
      float4 a = wl4[j];
      float4 c = wr4[j];
      al += f.x * a.x + f.y * a.y + f.z * a.z + f.w * a.w;
      ar += f.x * c.x + f.y * c.y + f.z * c.z + f.w * c.w;
    }
    #pragma unroll
    for (int o = 32; o > 0; o >>= 1) {
      al += __shfl_xor(al, o);
      ar += __shfl_xor(ar, o);
    }
    if (lane == 0) {
      el[node] = al + bl[0];
      er[node] = ar + br[0];
    }
  }
}

// ---------------- K2: gemm (blocks < NGEMM) + scan (last 49 blocks) ---------
// gemm: 512 thr = 8 waves, 32 rows x 256 cols, full K. feat staged as an
// fp32 fragment-image into 64 KB LDS via async global_load_lds (8 x 1KB per
// wave) with the fragment permutation + XOR swizzle applied to the GLOBAL
// source address (LDS linear, rule 21). Fragment reads convert fp32->bf16.
// Image: region h (0:k0..3, 1:k4..7) at Bs + h*32768; within region byte
// v*16, v = mg*1024 + kk*64 + slot, slot = (kgrp*16+row16)^(kk&7)^((row16&3)<<1).
#define GBM 32
__global__ __launch_bounds__(512, 4) void gemm_scan(const float* __restrict__ feat,
                        const unsigned short* __restrict__ Wtp,
                        const float* __restrict__ bias,
                        unsigned short* __restrict__ ftb,
                        const int* __restrict__ deg, int* __restrict__ off,
                        int* __restrict__ bsum, int* __restrict__ bscan,
                        int* __restrict__ done) {
  __shared__ char Bs[65536];                  // 64 KB (scan reuses as int buf)

  if (blockIdx.x >= NGEMM) {
    // ================= scan part =================
    int* ibuf = (int*)Bs;                     // [0..7] wave sums, [8] isLast
    int b = blockIdx.x - NGEMM;
    int t = threadIdx.x;
    int lane = t & 63, wid = t >> 6;
    int i0 = b * 1024 + 2 * t;
    int d0 = (i0 < N_NODES) ? deg[i0] : 0;
    int d1 = (i0 + 1 < N_NODES) ? deg[i0 + 1] : 0;
    int p = d0 + d1;
    int v = p;
    #pragma unroll
    for (int d = 1; d < 64; d <<= 1) {
      int x = __shfl_up(v, d);
      if (lane >= d) v += x;
    }
    if (lane == 63) ibuf[wid] = v;
    __syncthreads();
    if (wid == 0 && lane < 8) {
      int wv = ibuf[lane];
      int wo = wv;
      #pragma unroll
      for (int d = 1; d < 8; d <<= 1) {
        int x = __shfl_up(wv, d);
        if (lane >= d) wv += x;
      }
      ibuf[lane] = wv - wo;                   // exclusive wave offsets
    }
    __syncthreads();
    int excl = (v - p) + ibuf[wid];
    if (i0 < N_NODES) off[i0] = excl;
    if (i0 + 1 < N_NODES) off[i0 + 1] = excl + d0;
    if (t == 511) {
      atomicExch(&bsum[b], excl + p);         // block total, device-coherent
      __threadfence();
      int old = atomicAdd(done, 1);
      ibuf[8] = (old == NBLK_SCAN - 1);
    }
    __syncthreads();
    if (ibuf[8] && wid == 0) {                // last finisher scans bsums
      int bv = (lane < NBLK_SCAN) ? atomicAdd(&bsum[lane], 0) : 0;
      int orig = bv;
      #pragma unroll
      for (int d = 1; d < 64; d <<= 1) {
        int x = __shfl_up(bv, d);
        if (lane >= d) bv += x;
      }
      if (lane < NBLK_SCAN) bscan[lane] = bv - orig;   // exclusive
    }
    return;
  }

  // ================= gemm part =================
  const int tid  = threadIdx.x;
  const int lane = tid & 63;
  const int wv   = tid >> 6;          // 0..7
  const int m0   = blockIdx.x * GBM;

  // ---- stage: 8 async 1KB DMAs per wave, swizzled global source ----
  #pragma unroll
  for (int j = 0; j < 8; ++j) {
    int seg = wv * 8 + j;             // 0..63 (64 segs of 1KB = 64 KB)
    int u   = seg * 64 + lane;        // 16B unit index, 0..4095
    int h   = u >> 11;                // region: 0 = k0..3, 1 = k4..7
    int v   = u & 2047;
    int mgs = v >> 10;
    int kks = (v >> 6) & 15;
    int sp  = (v & 63) ^ (kks & 7);   // undo kk XOR
    int r0 = sp & 1;
    int r1 = ((sp >> 1) & 1) ^ r0;
    int r2 = ((sp >> 2) & 1) ^ r1;
    int r3 = (sp >> 3) & 1;
    int row16s = r0 | (r1 << 1) | (r2 << 2) | (r3 << 3);
    int kgrps  = sp >> 4;
    int grows = m0 + mgs * 16 + row16s;
    if (grows >= N_NODES) grows = N_NODES - 1;
    const float* gsrc = feat + (size_t)grows * IN_DIM + kks * 32 + kgrps * 8 + h * 4;
    gload_lds16(gsrc, Bs + seg * 1024);       // dst wave-uniform; HW adds lane*16
  }

  // W-frags for kk=0 issued before the barrier (independent of LDS)
  const int nt0 = wv * 2;
  const unsigned short* wp0 = Wtp + (((size_t)(nt0 + 0) * 16) * 64 + lane) * 8;
  const unsigned short* wp1 = Wtp + (((size_t)(nt0 + 1) * 16) * 64 + lane) * 8;
  short8 w0 = *(const short8*)wp0;
  short8 w1 = *(const short8*)wp1;
  __syncthreads();   // drains vmcnt(0): all DMAs landed

  // ---- compute: LDS fp32 frags -> bf16 + L2 W-frags (dist-1 prefetch) ----
  f32x4 acc[2][2];
  acc[0][0] = (f32x4)0.f; acc[0][1] = (f32x4)0.f;
  acc[1][0] = (f32x4)0.f; acc[1][1] = (f32x4)0.f;
  const char* BsA = Bs;
  const char* BsB = Bs + 32768;
  #pragma unroll
  for (int kk = 0; kk < 16; ++kk) {
    short8 nw0, nw1;
    if (kk < 15) {
      nw0 = *(const short8*)(wp0 + (size_t)(kk + 1) * 512);
      nw1 = *(const short8*)(wp1 + (size_t)(kk + 1) * 512);
    }
    int slotr = lane ^ (kk & 7) ^ ((lane & 3) << 1);
    int boff0 = ((0 * 1024) + kk * 64 + slotr) * 16;
    int boff1 = ((1 * 1024) + kk * 64 + slotr) * 16;
    float4 a0 = *(const float4*)(BsA + boff0);
    float4 b0 = *(const float4*)(BsB + boff0);
    float4 a1 = *(const float4*)(BsA + boff1);
    float4 b1 = *(const float4*)(BsB + boff1);
    short8 fa0, fa1;
    fa0[0] = (short)f2bf(a0.x); fa0[1] = (short)f2bf(a0.y);
    fa0[2] = (short)f2bf(a0.z); fa0[3] = (short)f2bf(a0.w);
    fa0[4] = (short)f2bf(b0.x); fa0[5] = (short)f2bf(b0.y);
    fa0[6] = (short)f2bf(b0.z); fa0[7] = (short)f2bf(b0.w);
    fa1[0] = (short)f2bf(a1.x); fa1[1] = (short)f2bf(a1.y);
    fa1[2] = (short)f2bf(a1.z); fa1[3] = (short)f2bf(a1.w);
    fa1[4] = (short)f2bf(b1.x); fa1[5] = (short)f2bf(b1.y);
    fa1[6] = (short)f2bf(b1.z); fa1[7] = (short)f2bf(b1.w);
    acc[0][0] = __builtin_amdgcn_mfma_f32_16x16x32_bf16(w0, fa0, acc[0][0], 0, 0, 0);
    acc[0][1] = __builtin_amdgcn_mfma_f32_16x16x32_bf16(w1, fa0, acc[0][1], 0, 0, 0);
    acc[1][0] = __builtin_amdgcn_mfma_f32_16x16x32_bf16(w0, fa1, acc[1][0], 0, 0, 0);
    acc[1][1] = __builtin_amdgcn_mfma_f32_16x16x32_bf16(w1, fa1, acc[1][1], 0, 0, 0);
    w0 = nw0; w1 = nw1;
  }

  const int l15 = lane & 15;
  #pragma unroll
  for (int mgi = 0; mgi < 2; ++mgi) {
    int row = m0 + mgi * 16 + l15;
    if (row < N_NODES) {
      unsigned short* orow = ftb + (size_t)row * OUT_DIM;
      #pragma unroll
      for (int t = 0; t < 2; ++t) {
        int col = (nt0 + t) * 16 + (lane >> 4) * 4;
        float4 bb = *(const float4*)(bias + col);
        f32x4 vv = acc[mgi][t];
        uint2 pv;
        pv.x = f2bf(vv[0] + bb.x) | (f2bf(vv[1] + bb.y) << 16);
        pv.y = f2bf(vv[2] + bb.z) | (f2bf(vv[3] + bb.w) << 16);
        *(uint2*)(orow + col) = pv;
      }
    }
  }
}

// ---------------- K3: scatter edges into CSR, 2 edges/thread ----------------
__global__ void scatter_edges(const int* __restrict__ src, const int* __restrict__ dst,
                              const float* __restrict__ el, const float* __restrict__ er,
                              const int* __restrict__ off, const int* __restrict__ bscan,
                              int* __restrict__ cnt, int2* __restrict__ sed) {
  int g = blockIdx.x * blockDim.x + threadIdx.x;
  int e = g * 2;
  if (e >= N_EDGES) return;
  int2 s2 = *(const int2*)(src + e);
  int2 d2 = *(const int2*)(dst + e);
  float el0 = el[s2.x], er0 = er[d2.x];
  float el1 = el[s2.y], er1 = er[d2.y];
  float ev0 = el0 + er0; ev0 = (ev0 > 0.f ? ev0 : 0.f) + 1.0f;
  float ev1 = el1 + er1; ev1 = (ev1 > 0.f ? ev1 : 0.f) + 1.0f;
  int base0 = off[d2.x] + bscan[d2.x >> 10];
  int base1 = off[d2.y] + bscan[d2.y >> 10];
  int pos0 = base0 + atomicAdd(&cnt[d2.x], 1);
  int pos1 = base1 + atomicAdd(&cnt[d2.y], 1);
  int2 pv0; pv0.x = s2.x; pv0.y = __float_as_int(ev0);
  int2 pv1; pv1.x = s2.y; pv1.y = __float_as_int(ev1);
  sed[pos0] = pv0;
  sed[pos1] = pv1;
}

// ---------------- K4: fused single-pass softmax + aggregation (8 chains) ----
__global__ __launch_bounds__(256) void aggregate(const int* __restrict__ off,
                         const int* __restrict__ bscan,
                         const int2* __restrict__ sed,
                         const unsigned short* __restrict__ ftb,
                         float* __restrict__ out) {
  int node = (int)((blockIdx.x * blockDim.x + threadIdx.x) >> 6);
  int lane = threadIdx.x & 63;
  if (node >= N_NODES) return;
  int start = off[node] + bscan[node >> 10];
  int end = (node == N_NODES - 1) ? N_EDGES
                                  : off[node + 1] + bscan[(node + 1) >> 10];

  f32x4 a0 = (f32x4)0.f, a1 = (f32x4)0.f, a2 = (f32x4)0.f, a3 = (f32x4)0.f;
  f32x4 a4 = (f32x4)0.f, a5 = (f32x4)0.f, a6 = (f32x4)0.f, a7 = (f32x4)0.f;
  float d0 = 0.f, d1 = 0.f, d2 = 0.f, d3 = 0.f;
  float d4 = 0.f, d5 = 0.f, d6 = 0.f, d7 = 0.f;

#define EDGE(acc, den, sidx, sval)                                   \
  {                                                                  \
    uint2 v = *((const uint2*)(ftb + (size_t)(sidx) * OUT_DIM) + lane); \
    float w = __expf(__int_as_float(sval));                          \
    den += w;                                                        \
    acc[0] += w * bf2f((unsigned short)(v.x & 0xFFFF));              \
    acc[1] += w * bf2f((unsigned short)(v.x >> 16));                 \
    acc[2] += w * bf2f((unsigned short)(v.y & 0xFFFF));              \
    acc[3] += w * bf2f((unsigned short)(v.y >> 16));                 \
  }

  int i = start;
  for (; i + 8 <= end; i += 8) {
    int4 s01 = *(const int4*)(sed + i);
    int4 s23 = *(const int4*)(sed + i + 2);
    int4 s45 = *(const int4*)(sed + i + 4);
    int4 s67 = *(const int4*)(sed + i + 6);
    EDGE(a0, d0, s01.x, s01.y) EDGE(a1, d1, s01.z, s01.w)
    EDGE(a2, d2, s23.x, s23.y) EDGE(a3, d3, s23.z, s23.w)
    EDGE(a4, d4, s45.x, s45.y) EDGE(a5, d5, s45.z, s45.w)
    EDGE(a6, d6, s67.x, s67.y) EDGE(a7, d7, s67.z, s67.w)
  }
  for (; i + 2 <= end; i += 2) {
    int4 s01 = *(const int4*)(sed + i);
    EDGE(a0, d0, s01.x, s01.y) EDGE(a1, d1, s01.z, s01.w)
  }
  for (; i < end; ++i) {
    int2 e0 = sed[i];
    EDGE(a0, d0, e0.x, e0.y)
  }
#undef EDGE

  f32x4 acc = ((a0 + a1) + (a2 + a3)) + ((a4 + a5) + (a6 + a7));
  float dsum = ((d0 + d1) + (d2 + d3)) + ((d4 + d5) + (d6 + d7));
  float inv = (end > start) ? 1.0f / dsum : 0.f;
  acc *= inv;
  __builtin_nontemporal_store(acc, (f32x4*)(out + (size_t)node * OUT_DIM + lane * 4));
}

// ---------------- launch ----------------------------------------------------
extern "C" void kernel_launch(void* const* d_in, const int* in_sizes, int n_in,
                              void* d_out, int out_size, void* d_ws, size_t ws_size,
                              hipStream_t stream) {
  const float* feat = (const float*)d_in[0];
  // d_in[1] = p (unused in eval path)
  const float* Wl = (const float*)d_in[2];
  const float* bl = (const float*)d_in[3];
  const float* Wr = (const float*)d_in[4];
  const float* br = (const float*)d_in[5];
  const float* W  = (const float*)d_in[6];
  const float* b  = (const float*)d_in[7];
  const int* src  = (const int*)d_in[8];
  const int* dst  = (const int*)d_in[9];
  float* out = (float*)d_out;

  char* ws = (char*)d_ws;
  float* el = (float*)ws;            ws += (size_t)N_NODES * 4;
  float* er = (float*)ws;            ws += (size_t)N_NODES * 4;
  unsigned short* Wtp = (unsigned short*)ws;  ws += (size_t)OUT_DIM * IN_DIM * 2;
  unsigned short* ftb = (unsigned short*)ws;  ws += (size_t)N_NODES * OUT_DIM * 2;
  int* deg  = (int*)ws;              ws += (size_t)N_NODES * 4;
  int* cnt  = (int*)ws;              ws += (size_t)N_NODES * 4;
  int* done = (int*)ws;              ws += 16 * 4;
  int* off  = (int*)ws;              ws += (size_t)(N_NODES + 1) * 4;
  int2* sed = (int2*)ws;             ws += (size_t)N_EDGES * 8;
  int* bsum = (int*)ws;              ws += 64 * 4;
  int* bscan = (int*)ws;             ws += 64 * 4;

  // zero deg + cnt + done (contiguous)
  hipMemsetAsync(deg, 0, ((size_t)N_NODES * 2 + 16) * 4, stream);

  wconv_deg_proj<<<WCONV_BLKS + DEG_BLKS + (N_NODES + 3) / 4, 256, 0, stream>>>(
      W, Wtp, dst, deg, feat, Wl, bl, Wr, br, el, er);
  gemm_scan<<<NGEMM + NBLK_SCAN, 512, 0, stream>>>(feat, Wtp, b, ftb, deg, off,
                                                   bsum, bscan, done);
  scatter_edges<<<(N_EDGES / 2 + 255) / 256, 256, 0, stream>>>(src, dst, el, er, off,
                                                               bscan, cnt, sed);
  aggregate<<<(N_NODES + 3) / 4, 256, 0, stream>>>(off, bscan, sed, ftb, out);
}

// Round 22
// 197.570 us; speedup vs baseline: 1.0633x; 1.0633x over previous
//
#include <hip/hip_runtime.h>
#include <math.h>
#include <stdint.h>

#define N_NODES 50000
#define N_EDGES 800000
#define IN_DIM  512
#define OUT_DIM 256
#define NBLK_SCAN 49   // ceil(50000/1024)
#define NGEMM 1563     // ceil(50000/32)

typedef __attribute__((ext_vector_type(8))) short short8;
typedef __attribute__((ext_vector_type(4))) float f32x4;

__device__ inline unsigned f2bf(float x) {
  unsigned u = __float_as_uint(x);
  return (u + 0x7FFFu + ((u >> 16) & 1u)) >> 16;   // RNE
}
__device__ inline float bf2f(unsigned short h) {
  return __uint_as_float(((unsigned)h) << 16);
}

// async 16B global->LDS copy (lds dest = wave-uniform base; HW adds lane*16)
__device__ inline void gload_lds16(const void* g, void* l) {
  __builtin_amdgcn_global_load_lds(
      (const __attribute__((address_space(1))) unsigned int*)g,
      (__attribute__((address_space(3))) unsigned int*)l, 16, 0, 0);
}

// ---------------- K1: fused wconv (blocks 0..511) + deg_count (rest) --------
#define WCONV_BLKS 512
__global__ __launch_bounds__(256) void wconv_deg(const float* __restrict__ W,
                                                 unsigned short* __restrict__ Wtp,
                                                 const int* __restrict__ dst,
                                                 int* __restrict__ deg) {
  if (blockIdx.x < WCONV_BLKS) {
    int i = blockIdx.x * 256 + threadIdx.x;   // over 131072
    int c = i & 255, k = i >> 8;
    int nt = c >> 4, kk = k >> 5;
    int lane = (((k & 31) >> 3) << 4) | (c & 15);
    int j = k & 7;
    Wtp[(((size_t)(nt * 16 + kk)) * 64 + lane) * 8 + j] =
        (unsigned short)f2bf(W[(size_t)k * OUT_DIM + c]);
  } else {
    int e = (blockIdx.x - WCONV_BLKS) * 256 + threadIdx.x;
    if (e < N_EDGES) atomicAdd(&deg[dst[e]], 1);
  }
}

// ---------------- K2: gemm+el/er (blocks < NGEMM) + scan (last 49) ----------
// feat staged ONCE as fp32 fragment-image into 64 KB LDS via async
// global_load_lds (swizzled global source, LDS linear). Compute loop converts
// fp32->bf16 for MFMA; wave wv also accumulates el/er partial dots for its
// kk in {2wv, 2wv+1} from the SAME register values (zero extra memory), then
// partials are shfl/LDS-reduced at the end.
#define GBM 32
__global__ __launch_bounds__(512, 4) void gemm_scan(const float* __restrict__ feat,
                        const unsigned short* __restrict__ Wtp,
                        const float* __restrict__ bias,
                        const float* __restrict__ Wl, const float* __restrict__ bl,
                        const float* __restrict__ Wr, const float* __restrict__ br,
                        unsigned short* __restrict__ ftb,
                        float* __restrict__ el, float* __restrict__ er,
                        const int* __restrict__ deg, int* __restrict__ off,
                        int* __restrict__ bsum, int* __restrict__ bscan,
                        int* __restrict__ done) {
  __shared__ char Bs[65536];                  // 64 KB (scan reuses as int buf)

  if (blockIdx.x >= NGEMM) {
    // ================= scan part =================
    int* ibuf = (int*)Bs;                     // [0..7] wave sums, [8] isLast
    int b = blockIdx.x - NGEMM;
    int t = threadIdx.x;
    int lane = t & 63, wid = t >> 6;
    int i0 = b * 1024 + 2 * t;
    int d0 = (i0 < N_NODES) ? deg[i0] : 0;
    int d1 = (i0 + 1 < N_NODES) ? deg[i0 + 1] : 0;
    int p = d0 + d1;
    int v = p;
    #pragma unroll
    for (int d = 1; d < 64; d <<= 1) {
      int x = __shfl_up(v, d);
      if (lane >= d) v += x;
    }
    if (lane == 63) ibuf[wid] = v;
    __syncthreads();
    if (wid == 0 && lane < 8) {
      int wv = ibuf[lane];
      int wo = wv;
      #pragma unroll
      for (int d = 1; d < 8; d <<= 1) {
        int x = __shfl_up(wv, d);
        if (lane >= d) wv += x;
      }
      ibuf[lane] = wv - wo;                   // exclusive wave offsets
    }
    __syncthreads();
    int excl = (v - p) + ibuf[wid];
    if (i0 < N_NODES) off[i0] = excl;
    if (i0 + 1 < N_NODES) off[i0 + 1] = excl + d0;
    if (t == 511) {
      atomicExch(&bsum[b], excl + p);         // block total, device-coherent
      __threadfence();
      int old = atomicAdd(done, 1);
      ibuf[8] = (old == NBLK_SCAN - 1);
    }
    __syncthreads();
    if (ibuf[8] && wid == 0) {                // last finisher scans bsums
      int bv = (lane < NBLK_SCAN) ? atomicAdd(&bsum[lane], 0) : 0;
      int orig = bv;
      #pragma unroll
      for (int d = 1; d < 64; d <<= 1) {
        int x = __shfl_up(bv, d);
        if (lane >= d) bv += x;
      }
      if (lane < NBLK_SCAN) bscan[lane] = bv - orig;   // exclusive
    }
    return;
  }

  // ================= gemm part =================
  const int tid  = threadIdx.x;
  const int lane = tid & 63;
  const int wv   = tid >> 6;          // 0..7
  const int m0   = blockIdx.x * GBM;

  // ---- stage: 8 async 1KB DMAs per wave, swizzled global source ----
  #pragma unroll
  for (int j = 0; j < 8; ++j) {
    int seg = wv * 8 + j;             // 0..63 (64 segs of 1KB = 64 KB)
    int u   = seg * 64 + lane;        // 16B unit index, 0..4095
    int h   = u >> 11;                // region: 0 = k+0..3, 1 = k+4..7
    int v   = u & 2047;
    int mgs = v >> 10;
    int kks = (v >> 6) & 15;
    int sp  = (v & 63) ^ (kks & 7);   // undo kk XOR
    int r0 = sp & 1;
    int r1 = ((sp >> 1) & 1) ^ r0;
    int r2 = ((sp >> 2) & 1) ^ r1;
    int r3 = (sp >> 3) & 1;
    int row16s = r0 | (r1 << 1) | (r2 << 2) | (r3 << 3);
    int kgrps  = sp >> 4;
    int grows = m0 + mgs * 16 + row16s;
    if (grows >= N_NODES) grows = N_NODES - 1;
    const float* gsrc = feat + (size_t)grows * IN_DIM + kks * 32 + kgrps * 8 + h * 4;
    gload_lds16(gsrc, Bs + seg * 1024);       // dst wave-uniform; HW adds lane*16
  }

  // W-frags for kk=0 issued before the barrier (independent of LDS)
  const int nt0 = wv * 2;
  const unsigned short* wp0 = Wtp + (((size_t)(nt0 + 0) * 16) * 64 + lane) * 8;
  const unsigned short* wp1 = Wtp + (((size_t)(nt0 + 1) * 16) * 64 + lane) * 8;
  short8 w0 = *(const short8*)wp0;
  short8 w1 = *(const short8*)wp1;
  __syncthreads();   // drains vmcnt(0): all DMAs landed

  // ---- compute: LDS fp32 frags -> bf16 + MFMA; el/er partials on the fly ---
  f32x4 acc[2][2];
  acc[0][0] = (f32x4)0.f; acc[0][1] = (f32x4)0.f;
  acc[1][0] = (f32x4)0.f; acc[1][1] = (f32x4)0.f;
  const char* BsA = Bs;
  const char* BsB = Bs + 32768;
  const int kgrp = lane >> 4;
  float elp = 0.f, erp = 0.f, el2p = 0.f, er2p = 0.f;
  #pragma unroll
  for (int kk = 0; kk < 16; ++kk) {
    short8 nw0, nw1;
    if (kk < 15) {
      nw0 = *(const short8*)(wp0 + (size_t)(kk + 1) * 512);
      nw1 = *(const short8*)(wp1 + (size_t)(kk + 1) * 512);
    }
    int slotr = lane ^ (kk & 7) ^ ((lane & 3) << 1);
    int boff0 = (kk * 64 + slotr) * 16;            // mg = 0
    int boff1 = ((1024 + kk * 64) + slotr) * 16;   // mg = 1
    float4 a0 = *(const float4*)(BsA + boff0);
    float4 b0 = *(const float4*)(BsB + boff0);
    float4 a1 = *(const float4*)(BsA + boff1);
    float4 b1 = *(const float4*)(BsB + boff1);
    // el/er: wave wv owns kk = 2wv, 2wv+1  (k = kk*32 + kgrp*8 + 0..7)
    if ((kk >> 1) == wv) {
      const float* wlp = Wl + kk * 32 + kgrp * 8;
      const float* wrp = Wr + kk * 32 + kgrp * 8;
      float4 wlA = *(const float4*)wlp;
      float4 wlB = *(const float4*)(wlp + 4);
      float4 wrA = *(const float4*)wrp;
      float4 wrB = *(const float4*)(wrp + 4);
      elp  += a0.x*wlA.x + a0.y*wlA.y + a0.z*wlA.z + a0.w*wlA.w
            + b0.x*wlB.x + b0.y*wlB.y + b0.z*wlB.z + b0.w*wlB.w;
      erp  += a0.x*wrA.x + a0.y*wrA.y + a0.z*wrA.z + a0.w*wrA.w
            + b0.x*wrB.x + b0.y*wrB.y + b0.z*wrB.z + b0.w*wrB.w;
      el2p += a1.x*wlA.x + a1.y*wlA.y + a1.z*wlA.z + a1.w*wlA.w
            + b1.x*wlB.x + b1.y*wlB.y + b1.z*wlB.z + b1.w*wlB.w;
      er2p += a1.x*wrA.x + a1.y*wrA.y + a1.z*wrA.z + a1.w*wrA.w
            + b1.x*wrB.x + b1.y*wrB.y + b1.z*wrB.z + b1.w*wrB.w;
    }
    short8 fa0, fa1;
    fa0[0] = (short)f2bf(a0.x); fa0[1] = (short)f2bf(a0.y);
    fa0[2] = (short)f2bf(a0.z); fa0[3] = (short)f2bf(a0.w);
    fa0[4] = (short)f2bf(b0.x); fa0[5] = (short)f2bf(b0.y);
    fa0[6] = (short)f2bf(b0.z); fa0[7] = (short)f2bf(b0.w);
    fa1[0] = (short)f2bf(a1.x); fa1[1] = (short)f2bf(a1.y);
    fa1[2] = (short)f2bf(a1.z); fa1[3] = (short)f2bf(a1.w);
    fa1[4] = (short)f2bf(b1.x); fa1[5] = (short)f2bf(b1.y);
    fa1[6] = (short)f2bf(b1.z); fa1[7] = (short)f2bf(b1.w);
    acc[0][0] = __builtin_amdgcn_mfma_f32_16x16x32_bf16(w0, fa0, acc[0][0], 0, 0, 0);
    acc[0][1] = __builtin_amdgcn_mfma_f32_16x16x32_bf16(w1, fa0, acc[0][1], 0, 0, 0);
    acc[1][0] = __builtin_amdgcn_mfma_f32_16x16x32_bf16(w0, fa1, acc[1][0], 0, 0, 0);
    acc[1][1] = __builtin_amdgcn_mfma_f32_16x16x32_bf16(w1, fa1, acc[1][1], 0, 0, 0);
    w0 = nw0; w1 = nw1;
  }

  // ---- C store ----
  const int l15 = lane & 15;
  #pragma unroll
  for (int mgi = 0; mgi < 2; ++mgi) {
    int row = m0 + mgi * 16 + l15;
    if (row < N_NODES) {
      unsigned short* orow = ftb + (size_t)row * OUT_DIM;
      #pragma unroll
      for (int t = 0; t < 2; ++t) {
        int col = (nt0 + t) * 16 + (lane >> 4) * 4;
        float4 bb = *(const float4*)(bias + col);
        f32x4 vv = acc[mgi][t];
        uint2 pv;
        pv.x = f2bf(vv[0] + bb.x) | (f2bf(vv[1] + bb.y) << 16);
        pv.y = f2bf(vv[2] + bb.z) | (f2bf(vv[3] + bb.w) << 16);
        *(uint2*)(orow + col) = pv;
      }
    }
  }

  // ---- el/er reduction: kgrp shfl, then LDS partials across waves ----
  #pragma unroll
  for (int o = 16; o < 64; o <<= 1) {
    elp  += __shfl_xor(elp,  o);
    erp  += __shfl_xor(erp,  o);
    el2p += __shfl_xor(el2p, o);
    er2p += __shfl_xor(er2p, o);
  }
  float* pel = (float*)Bs;            // [8][32]
  float* per = (float*)(Bs + 1024);   // [8][32]
  __syncthreads();                    // all MFMA reads of Bs complete
  if (lane < 16) {
    pel[wv * 32 + lane]      = elp;
    pel[wv * 32 + 16 + lane] = el2p;
    per[wv * 32 + lane]      = erp;
    per[wv * 32 + 16 + lane] = er2p;
  }
  __syncthreads();
  if (tid < 32) {
    float s = 0.f;
    #pragma unroll
    for (int w = 0; w < 8; ++w) s += pel[w * 32 + tid];
    int grow = m0 + tid;
    if (grow < N_NODES) el[grow] = s + bl[0];
  } else if (tid < 64) {
    int rr = tid - 32;
    float s = 0.f;
    #pragma unroll
    for (int w = 0; w < 8; ++w) s += per[w * 32 + rr];
    int grow = m0 + rr;
    if (grow < N_NODES) er[grow] = s + br[0];
  }
}

// ---------------- K3: scatter edges into CSR, 2 edges/thread ----------------
__global__ void scatter_edges(const int* __restrict__ src, const int* __restrict__ dst,
                              const float* __restrict__ el, const float* __restrict__ er,
                              const int* __restrict__ off, const int* __restrict__ bscan,
                              int* __restrict__ cnt, int2* __restrict__ sed) {
  int g = blockIdx.x * blockDim.x + threadIdx.x;
  int e = g * 2;
  if (e >= N_EDGES) return;
  int2 s2 = *(const int2*)(src + e);
  int2 d2 = *(const int2*)(dst + e);
  float el0 = el[s2.x], er0 = er[d2.x];
  float el1 = el[s2.y], er1 = er[d2.y];
  float ev0 = el0 + er0; ev0 = (ev0 > 0.f ? ev0 : 0.f) + 1.0f;
  float ev1 = el1 + er1; ev1 = (ev1 > 0.f ? ev1 : 0.f) + 1.0f;
  int base0 = off[d2.x] + bscan[d2.x >> 10];
  int base1 = off[d2.y] + bscan[d2.y >> 10];
  int pos0 = base0 + atomicAdd(&cnt[d2.x], 1);
  int pos1 = base1 + atomicAdd(&cnt[d2.y], 1);
  int2 pv0; pv0.x = s2.x; pv0.y = __float_as_int(ev0);
  int2 pv1; pv1.x = s2.y; pv1.y = __float_as_int(ev1);
  sed[pos0] = pv0;
  sed[pos1] = pv1;
}

// ---------------- K4: fused single-pass softmax + aggregation (8 chains) ----
__global__ __launch_bounds__(256) void aggregate(const int* __restrict__ off,
                         const int* __restrict__ bscan,
                         const int2* __restrict__ sed,
                         const unsigned short* __restrict__ ftb,
                         float* __restrict__ out) {
  int node = (int)((blockIdx.x * blockDim.x + threadIdx.x) >> 6);
  int lane = threadIdx.x & 63;
  if (node >= N_NODES) return;
  int start = off[node] + bscan[node >> 10];
  int end = (node == N_NODES - 1) ? N_EDGES
                                  : off[node + 1] + bscan[(node + 1) >> 10];

  f32x4 a0 = (f32x4)0.f, a1 = (f32x4)0.f, a2 = (f32x4)0.f, a3 = (f32x4)0.f;
  f32x4 a4 = (f32x4)0.f, a5 = (f32x4)0.f, a6 = (f32x4)0.f, a7 = (f32x4)0.f;
  float d0 = 0.f, d1 = 0.f, d2 = 0.f, d3 = 0.f;
  float d4 = 0.f, d5 = 0.f, d6 = 0.f, d7 = 0.f;

#define EDGE(acc, den, sidx, sval)                                   \
  {                                                                  \
    uint2 v = *((const uint2*)(ftb + (size_t)(sidx) * OUT_DIM) + lane); \
    float w = __expf(__int_as_float(sval));                          \
    den += w;                                                        \
    acc[0] += w * bf2f((unsigned short)(v.x & 0xFFFF));              \
    acc[1] += w * bf2f((unsigned short)(v.x >> 16));                 \
    acc[2] += w * bf2f((unsigned short)(v.y & 0xFFFF));              \
    acc[3] += w * bf2f((unsigned short)(v.y >> 16));                 \
  }

  int i = start;
  for (; i + 8 <= end; i += 8) {
    int4 s01 = *(const int4*)(sed + i);
    int4 s23 = *(const int4*)(sed + i + 2);
    int4 s45 = *(const int4*)(sed + i + 4);
    int4 s67 = *(const int4*)(sed + i + 6);
    EDGE(a0, d0, s01.x, s01.y) EDGE(a1, d1, s01.z, s01.w)
    EDGE(a2, d2, s23.x, s23.y) EDGE(a3, d3, s23.z, s23.w)
    EDGE(a4, d4, s45.x, s45.y) EDGE(a5, d5, s45.z, s45.w)
    EDGE(a6, d6, s67.x, s67.y) EDGE(a7, d7, s67.z, s67.w)
  }
  for (; i + 2 <= end; i += 2) {
    int4 s01 = *(const int4*)(sed + i);
    EDGE(a0, d0, s01.x, s01.y) EDGE(a1, d1, s01.z, s01.w)
  }
  for (; i < end; ++i) {
    int2 e0 = sed[i];
    EDGE(a0, d0, e0.x, e0.y)
  }
#undef EDGE

  f32x4 acc = ((a0 + a1) + (a2 + a3)) + ((a4 + a5) + (a6 + a7));
  float dsum = ((d0 + d1) + (d2 + d3)) + ((d4 + d5) + (d6 + d7));
  float inv = (end > start) ? 1.0f / dsum : 0.f;
  acc *= inv;
  __builtin_nontemporal_store(acc, (f32x4*)(out + (size_t)node * OUT_DIM + lane * 4));
}

// ---------------- launch ----------------------------------------------------
extern "C" void kernel_launch(void* const* d_in, const int* in_sizes, int n_in,
                              void* d_out, int out_size, void* d_ws, size_t ws_size,
                              hipStream_t stream) {
  const float* feat = (const float*)d_in[0];
  // d_in[1] = p (unused in eval path)
  const float* Wl = (const float*)d_in[2];
  const float* bl = (const float*)d_in[3];
  const float* Wr = (const float*)d_in[4];
  const float* br = (const float*)d_in[5];
  const float* W  = (const float*)d_in[6];
  const float* b  = (const float*)d_in[7];
  const int* src  = (const int*)d_in[8];
  const int* dst  = (const int*)d_in[9];
  float* out = (float*)d_out;

  char* ws = (char*)d_ws;
  float* el = (float*)ws;            ws += (size_t)N_NODES * 4;
  float* er = (float*)ws;            ws += (size_t)N_NODES * 4;
  unsigned short* Wtp = (unsigned short*)ws;  ws += (size_t)OUT_DIM * IN_DIM * 2;
  unsigned short* ftb = (unsigned short*)ws;  ws += (size_t)N_NODES * OUT_DIM * 2;
  int* deg  = (int*)ws;              ws += (size_t)N_NODES * 4;
  int* cnt  = (int*)ws;              ws += (size_t)N_NODES * 4;
  int* done = (int*)ws;              ws += 16 * 4;
  int* off  = (int*)ws;              ws += (size_t)(N_NODES + 1) * 4;
  int2* sed = (int2*)ws;             ws += (size_t)N_EDGES * 8;
  int* bsum = (int*)ws;              ws += 64 * 4;
  int* bscan = (int*)ws;             ws += 64 * 4;

  // zero deg + cnt + done (contiguous)
  hipMemsetAsync(deg, 0, ((size_t)N_NODES * 2 + 16) * 4, stream);

  wconv_deg<<<WCONV_BLKS + (N_EDGES + 255) / 256, 256, 0, stream>>>(W, Wtp, dst, deg);
  gemm_scan<<<NGEMM + NBLK_SCAN, 512, 0, stream>>>(feat, Wtp, b, Wl, bl, Wr, br,
                                                   ftb, el, er, deg, off, bsum,
                                                   bscan, done);
  scatter_edges<<<(N_EDGES / 2 + 255) / 256, 256, 0, stream>>>(src, dst, el, er, off,
                                                               bscan, cnt, sed);
  aggregate<<<(N_NODES + 3) / 4, 256, 0, stream>>>(off, bscan, sed, ftb, out);
}

// Round 23
// 192.221 us; speedup vs baseline: 1.0929x; 1.0278x over previous
//
#include <hip/hip_runtime.h>
#include <math.h>
#include <stdint.h>

#define N_NODES 50000
#define N_EDGES 800000
#define IN_DIM  512
#define OUT_DIM 256
#define NBLK_SCAN 49   // ceil(50000/1024)

typedef __attribute__((ext_vector_type(8))) short short8;
typedef __attribute__((ext_vector_type(4))) float f32x4;

__device__ inline unsigned f2bf(float x) {
  unsigned u = __float_as_uint(x);
  return (u + 0x7FFFu + ((u >> 16) & 1u)) >> 16;   // RNE
}
__device__ inline float bf2f(unsigned short h) {
  return __uint_as_float(((unsigned)h) << 16);
}

// ---------------- K1: W [512][256] -> Wtp frag-major bf16 -------------------
// Wtp[((nt*16+kk)*64 + lane)*8 + j] = bf16(W[k][c]), k=kk*32+(lane>>4)*8+j,
// c = nt*16 + (lane&15).
__global__ __launch_bounds__(256) void wconv(const float* __restrict__ W,
                                             unsigned short* __restrict__ Wtp) {
  int i = blockIdx.x * 256 + threadIdx.x;   // over 131072
  int c = i & 255, k = i >> 8;              // coalesced read over c
  int nt = c >> 4, kk = k >> 5;
  int lane = (((k & 31) >> 3) << 4) | (c & 15);
  int j = k & 7;
  Wtp[(((size_t)(nt * 16 + kk)) * 64 + lane) * 8 + j] =
      (unsigned short)f2bf(W[(size_t)k * OUT_DIM + c]);
}

// ---------------- K2: ft = bf16(feat @ W + b), feat-in-LDS, W from L2 -------
// block: 512 thr = 8 waves; tile = 32 rows x 256 cols, full K.
// Stage (MLP=8): lane owns row r=wv*4+(lane>>4), chunks c4=(lane&15)+16j,
// j=0..7; el/er reduced over the 16 lanes of the row group.
// LDS slot swizzle: S = (kgrp*16+row16) ^ (kk&7) ^ ((row16&3)<<1).
#define GBM 32
__global__ __launch_bounds__(512) void gemm_mfma(const float* __restrict__ feat,
                        const unsigned short* __restrict__ Wtp,
                        const float* __restrict__ bias,
                        const float* __restrict__ Wl, const float* __restrict__ bl,
                        const float* __restrict__ Wr, const float* __restrict__ br,
                        unsigned short* __restrict__ ftb,
                        float* __restrict__ el, float* __restrict__ er) {
  __shared__ unsigned short Bs[16384];        // 32 KB
  const int tid  = threadIdx.x;
  const int lane = tid & 63;
  const int wv   = tid >> 6;          // 0..7
  const int m0   = blockIdx.x * GBM;

  const int l15   = lane & 15;
  const int r     = wv * 4 + (lane >> 4);     // row within tile, 0..31
  const int row16 = r & 15;
  const int mg    = r >> 4;
  const int kgrp  = (l15 >> 1) & 3;
  const int b3    = l15 >> 3;
  const int h     = lane & 1;
  int grow = m0 + r;
  int gc   = grow < N_NODES ? grow : N_NODES - 1;
  const float4* frow = (const float4*)(feat + (size_t)gc * IN_DIM);
  const float4* wl4  = (const float4*)Wl;
  const float4* wr4  = (const float4*)Wr;

  float elp = 0.f, erp = 0.f;
  #pragma unroll
  for (int half = 0; half < 2; ++half) {
    float4 f[4], wlv[4], wrv[4];
    #pragma unroll
    for (int q = 0; q < 4; ++q) {
      int c4 = l15 + 16 * (half * 4 + q);
      f[q]   = frow[c4];
      wlv[q] = wl4[c4];
      wrv[q] = wr4[c4];
    }
    #pragma unroll
    for (int q = 0; q < 4; ++q) {
      int j = half * 4 + q;
      elp += f[q].x * wlv[q].x + f[q].y * wlv[q].y + f[q].z * wlv[q].z + f[q].w * wlv[q].w;
      erp += f[q].x * wrv[q].x + f[q].y * wrv[q].y + f[q].z * wrv[q].z + f[q].w * wrv[q].w;
      uint2 pv;
      pv.x = f2bf(f[q].x) | (f2bf(f[q].y) << 16);
      pv.y = f2bf(f[q].z) | (f2bf(f[q].w) << 16);
      int kk   = 2 * j + b3;
      int slot = (kgrp * 16 + row16) ^ (kk & 7) ^ ((row16 & 3) << 1);
      *(uint2*)((char*)Bs + (((mg * 16 + kk) * 64) + slot) * 16 + h * 8) = pv;
    }
  }
  #pragma unroll
  for (int o = 1; o < 16; o <<= 1) {
    elp += __shfl_xor(elp, o);
    erp += __shfl_xor(erp, o);
  }
  if (l15 == 0 && grow < N_NODES) {
    el[grow] = elp + bl[0];
    er[grow] = erp + br[0];
  }
  __syncthreads();

  // compute: LDS feat + L2 W-frags (distance-1 prefetch) + MFMA
  f32x4 acc[2][2];
  acc[0][0] = (f32x4)0.f; acc[0][1] = (f32x4)0.f;
  acc[1][0] = (f32x4)0.f; acc[1][1] = (f32x4)0.f;
  const int nt0 = wv * 2;
  const unsigned short* wp0 = Wtp + (((size_t)(nt0 + 0) * 16) * 64 + lane) * 8;
  const unsigned short* wp1 = Wtp + (((size_t)(nt0 + 1) * 16) * 64 + lane) * 8;
  const int rlane = lane & 15;
  short8 w0 = *(const short8*)wp0;
  short8 w1 = *(const short8*)wp1;
  #pragma unroll
  for (int kk = 0; kk < 16; ++kk) {
    short8 nw0, nw1;
    if (kk < 15) {
      nw0 = *(const short8*)(wp0 + (size_t)(kk + 1) * 512);
      nw1 = *(const short8*)(wp1 + (size_t)(kk + 1) * 512);
    }
    int slotr = lane ^ (kk & 7) ^ ((rlane & 3) << 1);
    short8 fa0 = *(const short8*)((char*)Bs + (((0 * 16 + kk) * 64) + slotr) * 16);
    short8 fa1 = *(const short8*)((char*)Bs + (((1 * 16 + kk) * 64) + slotr) * 16);
    acc[0][0] = __builtin_amdgcn_mfma_f32_16x16x32_bf16(w0, fa0, acc[0][0], 0, 0, 0);
    acc[0][1] = __builtin_amdgcn_mfma_f32_16x16x32_bf16(w1, fa0, acc[0][1], 0, 0, 0);
    acc[1][0] = __builtin_amdgcn_mfma_f32_16x16x32_bf16(w0, fa1, acc[1][0], 0, 0, 0);
    acc[1][1] = __builtin_amdgcn_mfma_f32_16x16x32_bf16(w1, fa1, acc[1][1], 0, 0, 0);
    w0 = nw0; w1 = nw1;
  }

  #pragma unroll
  for (int mgi = 0; mgi < 2; ++mgi) {
    int row = m0 + mgi * 16 + l15;
    if (row < N_NODES) {
      unsigned short* orow = ftb + (size_t)row * OUT_DIM;
      #pragma unroll
      for (int t = 0; t < 2; ++t) {
        int col = (nt0 + t) * 16 + (lane >> 4) * 4;
        float4 bb = *(const float4*)(bias + col);
        f32x4 vv = acc[mgi][t];
        uint2 pv;
        pv.x = f2bf(vv[0] + bb.x) | (f2bf(vv[1] + bb.y) << 16);
        pv.y = f2bf(vv[2] + bb.z) | (f2bf(vv[3] + bb.w) << 16);
        *(uint2*)(orow + col) = pv;
      }
    }
  }
}

// ---------------- K3: degree histogram --------------------------------------
__global__ void deg_count(const int* __restrict__ dst, int* __restrict__ deg) {
  int e = blockIdx.x * blockDim.x + threadIdx.x;
  if (e < N_EDGES) atomicAdd(&deg[dst[e]], 1);
}

// ---------------- K4: parallel exclusive scan (3 stages, shfl-based) --------
__global__ __launch_bounds__(1024) void scan_local(const int* __restrict__ deg,
                                                   int* __restrict__ off,
                                                   int* __restrict__ bsum) {
  __shared__ int wsum[16];
  int b = blockIdx.x, t = threadIdx.x, i = b * 1024 + t;
  int lane = t & 63, wid = t >> 6;
  int v0 = (i < N_NODES) ? deg[i] : 0;
  int v = v0;
  #pragma unroll
  for (int d = 1; d < 64; d <<= 1) {
    int x = __shfl_up(v, d);
    if (lane >= d) v += x;
  }
  if (lane == 63) wsum[wid] = v;
  __syncthreads();
  if (wid == 0) {
    int wv = (lane < 16) ? wsum[lane] : 0;
    int wo = wv;
    #pragma unroll
    for (int d = 1; d < 16; d <<= 1) {
      int x = __shfl_up(wv, d);
      if (lane >= d) wv += x;
    }
    if (lane < 16) wsum[lane] = wv - wo;   // exclusive wave offsets
    if (lane == 15) bsum[b] = wv;          // block total
  }
  __syncthreads();
  if (i < N_NODES) off[i] = (v - v0) + wsum[wid];
}

__global__ void scan_bsums(const int* __restrict__ bsum, int* __restrict__ bscan,
                           int* __restrict__ offN) {
  int t = threadIdx.x;                      // 64 threads, 1 block
  int v = (t < NBLK_SCAN) ? bsum[t] : 0;
  int orig = v;
  for (int d = 1; d < 64; d <<= 1) {
    int x = __shfl_up(v, d);
    if (t >= d) v += x;
  }
  if (t < NBLK_SCAN) bscan[t] = v - orig;   // exclusive
  if (t == NBLK_SCAN - 1) offN[0] = v;      // total == N_EDGES
}

__global__ void add_bscan(int* __restrict__ off, const int* __restrict__ bscan) {
  int i = blockIdx.x * 256 + threadIdx.x;
  if (i < N_NODES) off[i] += bscan[i >> 10];
}

// ---------------- K5: scatter edges into CSR + edge score (int2 packed) -----
__global__ void scatter_edges(const int* __restrict__ src, const int* __restrict__ dst,
                              const float* __restrict__ el, const float* __restrict__ er,
                              const int* __restrict__ off, int* __restrict__ cnt,
                              int2* __restrict__ sed) {
  int e = blockIdx.x * blockDim.x + threadIdx.x;
  if (e >= N_EDGES) return;
  int s = src[e], d = dst[e];
  int pos = off[d] + atomicAdd(&cnt[d], 1);
  float ev = el[s] + er[d];
  ev = (ev > 0.f ? ev : 0.f) + 1.0f;
  int2 pv; pv.x = s; pv.y = __float_as_int(ev);
  sed[pos] = pv;
}

// ---------------- K6: fused single-pass softmax + aggregation ---------------
__global__ __launch_bounds__(256) void aggregate(const int* __restrict__ off,
                         const int2* __restrict__ sed,
                         const unsigned short* __restrict__ ftb,
                         float* __restrict__ out) {
  int node = (int)((blockIdx.x * blockDim.x + threadIdx.x) >> 6);
  int lane = threadIdx.x & 63;
  if (node >= N_NODES) return;
  int start = off[node], end = off[node + 1];

  f32x4 a0 = (f32x4)0.f, a1 = (f32x4)0.f, a2 = (f32x4)0.f, a3 = (f32x4)0.f;
  float d0 = 0.f, d1 = 0.f, d2 = 0.f, d3 = 0.f;

#define EDGE(acc, den, sidx, sval)                                   \
  {                                                                  \
    uint2 v = *((const uint2*)(ftb + (size_t)(sidx) * OUT_DIM) + lane); \
    float w = __expf(__int_as_float(sval));                          \
    den += w;                                                        \
    acc[0] += w * bf2f((unsigned short)(v.x & 0xFFFF));              \
    acc[1] += w * bf2f((unsigned short)(v.x >> 16));                 \
    acc[2] += w * bf2f((unsigned short)(v.y & 0xFFFF));              \
    acc[3] += w * bf2f((unsigned short)(v.y >> 16));                 \
  }

  int i = start;
  for (; i + 8 <= end; i += 8) {
    int4 s01 = *(const int4*)(sed + i);
    int4 s23 = *(const int4*)(sed + i + 2);
    int4 s45 = *(const int4*)(sed + i + 4);
    int4 s67 = *(const int4*)(sed + i + 6);
    EDGE(a0, d0, s01.x, s01.y) EDGE(a1, d1, s01.z, s01.w)
    EDGE(a2, d2, s23.x, s23.y) EDGE(a3, d3, s23.z, s23.w)
    EDGE(a0, d0, s45.x, s45.y) EDGE(a1, d1, s45.z, s45.w)
    EDGE(a2, d2, s67.x, s67.y) EDGE(a3, d3, s67.z, s67.w)
  }
  for (; i + 2 <= end; i += 2) {
    int4 s01 = *(const int4*)(sed + i);
    EDGE(a0, d0, s01.x, s01.y) EDGE(a1, d1, s01.z, s01.w)
  }
  for (; i < end; ++i) {
    int2 e0 = sed[i];
    EDGE(a0, d0, e0.x, e0.y)
  }
#undef EDGE

  f32x4 acc = (a0 + a1) + (a2 + a3);
  float dsum = (d0 + d1) + (d2 + d3);
  float inv = (end > start) ? 1.0f / dsum : 0.f;
  acc *= inv;
  __builtin_nontemporal_store(acc, (f32x4*)(out + (size_t)node * OUT_DIM + lane * 4));
}

// ---------------- launch ----------------------------------------------------
extern "C" void kernel_launch(void* const* d_in, const int* in_sizes, int n_in,
                              void* d_out, int out_size, void* d_ws, size_t ws_size,
                              hipStream_t stream) {
  const float* feat = (const float*)d_in[0];
  // d_in[1] = p (unused in eval path)
  const float* Wl = (const float*)d_in[2];
  const float* bl = (const float*)d_in[3];
  const float* Wr = (const float*)d_in[4];
  const float* br = (const float*)d_in[5];
  const float* W  = (const float*)d_in[6];
  const float* b  = (const float*)d_in[7];
  const int* src  = (const int*)d_in[8];
  const int* dst  = (const int*)d_in[9];
  float* out = (float*)d_out;

  char* ws = (char*)d_ws;
  float* el = (float*)ws;            ws += (size_t)N_NODES * 4;
  float* er = (float*)ws;            ws += (size_t)N_NODES * 4;
  unsigned short* Wtp = (unsigned short*)ws;  ws += (size_t)OUT_DIM * IN_DIM * 2;
  unsigned short* ftb = (unsigned short*)ws;  ws += (size_t)N_NODES * OUT_DIM * 2;
  int* deg  = (int*)ws;              ws += (size_t)N_NODES * 4;
  int* cnt  = (int*)ws;              ws += (size_t)N_NODES * 4;
  int* off  = (int*)ws;              ws += (size_t)(N_NODES + 1) * 4;
  int2* sed = (int2*)ws;             ws += (size_t)N_EDGES * 8;
  int* bsum = (int*)ws;              ws += 64 * 4;
  int* bscan = (int*)ws;             ws += 64 * 4;

  hipMemsetAsync(deg, 0, (size_t)N_NODES * 4 * 2, stream);   // deg + cnt

  wconv<<<(OUT_DIM * IN_DIM) / 256, 256, 0, stream>>>(W, Wtp);
  gemm_mfma<<<(N_NODES + GBM - 1) / GBM, 512, 0, stream>>>(feat, Wtp, b, Wl, bl, Wr, br,
                                                           ftb, el, er);
  deg_count<<<(N_EDGES + 255) / 256, 256, 0, stream>>>(dst, deg);
  scan_local<<<NBLK_SCAN, 1024, 0, stream>>>(deg, off, bsum);
  scan_bsums<<<1, 64, 0, stream>>>(bsum, bscan, off + N_NODES);
  add_bscan<<<(N_NODES + 255) / 256, 256, 0, stream>>>(off, bscan);
  scatter_edges<<<(N_EDGES + 255) / 256, 256, 0, stream>>>(src, dst, el, er, off, cnt, sed);
  aggregate<<<(N_NODES + 3) / 4, 256, 0, stream>>>(off, sed, ftb, out);
}